// Round 11
// baseline (2550.940 us; speedup 1.0000x reference)
//
#include <hip/hip_runtime.h>
#include <stdint.h>

#define B_   64
#define T_   512
#define NIN_ 256
#define N_   512

typedef _Float16 half8   __attribute__((ext_vector_type(8)));
typedef float    f32x4   __attribute__((ext_vector_type(4)));
typedef _Float16 half2_t __attribute__((ext_vector_type(2)));

__device__ __forceinline__ float fast_tanh(float x) {
  float e = __expf(2.0f * x);
  return 1.0f - 2.0f / (e + 1.0f);
}
__device__ __forceinline__ unsigned int packh2(float a, float b) {
  half2_t h; h[0] = (_Float16)a; h[1] = (_Float16)b;
  return __builtin_bit_cast(unsigned int, h);
}

// Fused kernel, 256 blocks x 1024 threads (1 block/CU -> all co-resident).
//   blocks 0..7   : scan. group g = blk>>1 (16 batches), half e = blk&1
//                   (256 neurons). 16 waves x one 16x16x32 f16 tile
//                   (16 neurons x 16 batches, FULL K=512) -> no partial-sum
//                   reduce, ONE barrier/step. Exchange with the single
//                   partner block via tagged u64 agent atomics (2 polls/lane).
//   blocks 8..255 : xproj GEMM, t-chunk-major, release-fenced chunk flags.
__global__ __launch_bounds__(1024, 1) void rnn_fused(
    const float* __restrict__ x, const float* __restrict__ Wih,
    const float* __restrict__ Whh, float* __restrict__ out,
    unsigned long long* __restrict__ ex, int* __restrict__ ctrl) {
  const int blk = blockIdx.x;
  const int tid = threadIdx.x;

  __shared__ float xt[32][132];
  __shared__ float wt[32][132];
  __shared__ __align__(16) unsigned int th[2][16][260];  // [slot][batch][pair]

  if (blk >= 8) {
    // ================= xproj role (R10 structure) =================
    const int tm = tid & 15;     // 8-row group
    const int tn = tid >> 4;     // 0..63 -> 2 cols
    for (int tau = blk - 8; tau < 1024; tau += 248) {
      const int tc = tau >> 8;   // t-chunk; chunk-0 tiles first
      const int j  = tau & 255;
      const int bb = j >> 2;
      const int bn = j & 3;
      const int m0 = (bb * 4 + tc) << 7;
      const int nn0 = bn << 7;

      float acc[8][2];
#pragma unroll
      for (int i = 0; i < 8; ++i) { acc[i][0] = 0.f; acc[i][1] = 0.f; }

      for (int ko = 0; ko < NIN_; ko += 32) {
        const int mm = tid >> 3;            // 0..127
        const int k4 = (tid & 7) << 2;      // 0..28
        const float4 vx = *(const float4*)(x + (size_t)(m0 + mm) * NIN_ + ko + k4);
        xt[k4 + 0][mm] = vx.x; xt[k4 + 1][mm] = vx.y;
        xt[k4 + 2][mm] = vx.z; xt[k4 + 3][mm] = vx.w;
        const float4 vw = *(const float4*)(Wih + (size_t)(nn0 + mm) * NIN_ + ko + k4);
        wt[k4 + 0][mm] = vw.x; wt[k4 + 1][mm] = vw.y;
        wt[k4 + 2][mm] = vw.z; wt[k4 + 3][mm] = vw.w;
        __syncthreads();
#pragma unroll 4
        for (int kk = 0; kk < 32; ++kk) {
          float a[8];
          *(float4*)&a[0] = *(const float4*)&xt[kk][8 * tm];
          *(float4*)&a[4] = *(const float4*)&xt[kk][8 * tm + 4];
          const float2 bv = *(const float2*)&wt[kk][2 * tn];
#pragma unroll
          for (int i = 0; i < 8; ++i) {
            acc[i][0] = fmaf(a[i], bv.x, acc[i][0]);
            acc[i][1] = fmaf(a[i], bv.y, acc[i][1]);
          }
        }
        __syncthreads();
      }
#pragma unroll
      for (int i = 0; i < 8; ++i) {
        float2 st; st.x = acc[i][0]; st.y = acc[i][1];
        *(float2*)(out + (size_t)(m0 + 8 * tm + i) * N_ + nn0 + 2 * tn) = st;
      }
      __threadfence();
      __syncthreads();
      if (tid == 0)
        __hip_atomic_fetch_add(&ctrl[tc], 1, __ATOMIC_RELEASE,
                               __HIP_MEMORY_SCOPE_AGENT);
    }
    return;
  }

  // ================= scan role =================
  const int g = blk >> 1;        // group: batches g*16 .. g*16+15
  const int e = blk & 1;         // neuron half: e*256 .. e*256+255
  const int er = e ^ 1;          // remote half
  const int wv = tid >> 6;
  const int l  = tid & 63;
  const int col = l & 15;        // B/D col = batch-in-group (R5-verified)
  const int hi  = l >> 4;        // k-octet / row-quad selector

  // ---- A-fragments: 16 named half8 (R5 sigma), asm-pinned (R8) ----
  const int arow = e * 256 + wv * 16 + col;       // neuron of my A-row
  const float* wbase = Whh + (size_t)arow * N_ + hi * 8;
#define LDW(KS)                                                        \
  half8 wf##KS;                                                        \
  {                                                                    \
    const float* wr = wbase + (KS) * 32;                               \
    const float4 w0 = *(const float4*)wr;                              \
    const float4 w1 = *(const float4*)(wr + 4);                        \
    wf##KS[0] = (_Float16)w0.x; wf##KS[1] = (_Float16)w0.y;            \
    wf##KS[2] = (_Float16)w0.z; wf##KS[3] = (_Float16)w0.w;            \
    wf##KS[4] = (_Float16)w1.x; wf##KS[5] = (_Float16)w1.y;            \
    wf##KS[6] = (_Float16)w1.z; wf##KS[7] = (_Float16)w1.w;            \
  }
  LDW(0) LDW(1) LDW(2) LDW(3) LDW(4) LDW(5) LDW(6) LDW(7)
  LDW(8) LDW(9) LDW(10) LDW(11) LDW(12) LDW(13) LDW(14) LDW(15)
#undef LDW
  asm volatile("" : "+v"(wf0), "+v"(wf1), "+v"(wf2), "+v"(wf3),
                    "+v"(wf4), "+v"(wf5), "+v"(wf6), "+v"(wf7));
  asm volatile("" : "+v"(wf8), "+v"(wf9), "+v"(wf10), "+v"(wf11),
                    "+v"(wf12), "+v"(wf13), "+v"(wf14), "+v"(wf15));

  // ---- per-lane constants ----
  const int gb = g * 16 + col;                     // global batch
  const size_t outrow = (size_t)gb * T_ * N_;
  const int n0 = e * 256 + wv * 16 + hi * 4;       // first D-row neuron
  const int pp = wv * 8 + hi * 2;                  // pair idx in half (0..127)
  // poller: 2 remote packets (partner publishes all at once)
  const int pr  = tid & 127;                       // pair 0..127
  const int pb0 = tid >> 7;                        // batch 0..7 (and +8)

  // ---- gate on xproj chunk 0, then stage FULL h_1 (both halves, from out) --
  if (tid == 0) {
    while (__hip_atomic_load(&ctrl[0], __ATOMIC_ACQUIRE,
                             __HIP_MEMORY_SCOPE_AGENT) < 256)
      __builtin_amdgcn_s_sleep(1);
  }
  __syncthreads();
#pragma unroll
  for (int ps = 0; ps < 4; ++ps) {
    const int i = ps * 1024 + tid;     // 0..4095
    const int b = i >> 8;
    const int p = i & 255;
    const float2 h0 = *(const float2*)(out + (size_t)(g * 16 + b) * T_ * N_ + 2 * p);
    th[0][b][p] = packh2(fast_tanh(h0.x), fast_tanh(h0.y));
  }

  for (int t = 1; t < T_; ++t) {
    if ((t & 127) == 0) {              // xp chunk gate (t = 128, 256, 384)
      if (tid == 0) {
        while (__hip_atomic_load(&ctrl[t >> 7], __ATOMIC_ACQUIRE,
                                 __HIP_MEMORY_SCOPE_AGENT) < 256)
          __builtin_amdgcn_s_sleep(1);
      }
      __syncthreads();
    }

    // xp prefetch (hidden under the poll)
    const float4 xp = *(const float4*)(out + outrow + (size_t)t * N_ + n0);

    // poll 2 remote packets (tag t-1) from the single partner block
    if (t >= 2) {
      const int slot = (t - 1) & 1;
      const unsigned long long* a0 =
          &ex[(((size_t)(g * 2 + slot) * 2 + er) * 16 + pb0) * 128 + pr];
      const unsigned long long* a1 = a0 + (size_t)8 * 128;
      unsigned long long v0, v1;
      unsigned got = 0;
      do {
        if (!(got & 1)) {
          v0 = __hip_atomic_load(a0, __ATOMIC_RELAXED, __HIP_MEMORY_SCOPE_AGENT);
          if ((unsigned int)(v0 >> 32) == (unsigned int)(t - 1)) got |= 1;
        }
        if (!(got & 2)) {
          v1 = __hip_atomic_load(a1, __ATOMIC_RELAXED, __HIP_MEMORY_SCOPE_AGENT);
          if ((unsigned int)(v1 >> 32) == (unsigned int)(t - 1)) got |= 2;
        }
      } while (got != 3u);
      th[slot][pb0][er * 128 + pr]     = (unsigned int)v0;
      th[slot][pb0 + 8][er * 128 + pr] = (unsigned int)v1;
    }
    __syncthreads();   // the ONE barrier: th[(t-1)&1] complete

    // ---- 16 chained MFMA over full K=512 (R5-verified fragments) ----
    const unsigned int* tb = &th[(t - 1) & 1][col][hi * 4];
    f32x4 acc = {0.f, 0.f, 0.f, 0.f};
#define MM(KS)                                                             \
  {                                                                        \
    const uint4 bv = *(const uint4*)(tb + (KS) * 16);                      \
    acc = __builtin_amdgcn_mfma_f32_16x16x32_f16(                          \
        wf##KS, __builtin_bit_cast(half8, bv), acc, 0, 0, 0);              \
  }
    MM(0) MM(1) MM(2) MM(3) MM(4) MM(5) MM(6) MM(7)
    MM(8) MM(9) MM(10) MM(11) MM(12) MM(13) MM(14) MM(15)
#undef MM

    // ---- epilogue: publish FIRST (cross-CU critical path) ----
    const float y0 = acc[0] + xp.x;
    const float y1 = acc[1] + xp.y;
    const float y2 = acc[2] + xp.z;
    const float y3 = acc[3] + xp.w;
    const unsigned int p0 = packh2(fast_tanh(y0), fast_tanh(y1));
    const unsigned int p1 = packh2(fast_tanh(y2), fast_tanh(y3));
    const size_t eb = (((size_t)(g * 2 + (t & 1)) * 2 + e) * 16 + col) * 128 + pp;
    const unsigned long long tg = (unsigned long long)(unsigned int)t << 32;
    __hip_atomic_store(&ex[eb],     tg | p0, __ATOMIC_RELAXED,
                       __HIP_MEMORY_SCOPE_AGENT);
    __hip_atomic_store(&ex[eb + 1], tg | p1, __ATOMIC_RELAXED,
                       __HIP_MEMORY_SCOPE_AGENT);
    th[t & 1][col][e * 128 + pp]     = p0;
    th[t & 1][col][e * 128 + pp + 1] = p1;
    *(float4*)(out + outrow + (size_t)t * N_ + n0) = make_float4(y0, y1, y2, y3);
    // next iteration's barrier provides all separation (double-buffer parity)
  }
}

extern "C" void kernel_launch(void* const* d_in, const int* in_sizes, int n_in,
                              void* d_out, int out_size, void* d_ws, size_t ws_size,
                              hipStream_t stream) {
  const float* x   = (const float*)d_in[0];
  const float* Wih = (const float*)d_in[1];
  const float* Whh = (const float*)d_in[2];
  float* out = (float*)d_out;
  unsigned long long* ex = (unsigned long long*)d_ws;   // 256 KiB exchange
  int* ctrl = (int*)((char*)d_ws + 262144);             // 4 chunk flags

  hipMemsetAsync(d_ws, 0, 262144 + 64, stream);
  rnn_fused<<<256, 1024, 0, stream>>>(x, Wih, Whh, out, ex, ctrl);
}

// Round 13
// 1153.346 us; speedup vs baseline: 2.2118x; 2.2118x over previous
//
#include <hip/hip_runtime.h>
#include <stdint.h>

#define B_   64
#define T_   512
#define NIN_ 256
#define N_   512

typedef _Float16 half2_t __attribute__((ext_vector_type(2)));

#if defined(__has_builtin)
#if __has_builtin(__builtin_amdgcn_fdot2)
#define HAVE_FDOT2 1
#endif
#endif

__device__ __forceinline__ float dot2acc(unsigned int a, unsigned int b, float c) {
#ifdef HAVE_FDOT2
  return __builtin_amdgcn_fdot2(__builtin_bit_cast(half2_t, a),
                                __builtin_bit_cast(half2_t, b), c, false);
#else
  half2_t ha = __builtin_bit_cast(half2_t, a), hb = __builtin_bit_cast(half2_t, b);
  c += (float)ha[0] * (float)hb[0];
  c += (float)ha[1] * (float)hb[1];
  return c;
#endif
}

__device__ __forceinline__ float fast_tanh(float x) {
  float e = __expf(2.0f * x);
  return 1.0f - 2.0f / (e + 1.0f);
}
__device__ __forceinline__ unsigned int packh2(float a, float b) {
  half2_t h; h[0] = (_Float16)a; h[1] = (_Float16)b;
  return __builtin_bit_cast(unsigned int, h);
}

// Quarter-interleaved LDS index for tanh pair p (conflict-free b128 broadcast)
__device__ __forceinline__ int thp_idx(int p) {
  return (((p >> 2) & 15) << 4) + ((p >> 6) << 2) + (p & 3);
}

// Fused kernel, 448 blocks x 512 thr.
// __launch_bounds__(512, 4) is a LIVENESS requirement: it caps VGPR at 128 so
// 2 blocks/CU are resident -> all 448 blocks co-resident (448 <= 512 slots) ->
// the xproj producers always run concurrently with the gated scan consumers.
// (R12 omitted the ",4" -> 1 block/CU -> 256-resident -> deadlock.)
//   blocks 0..255  : R4 scan VERBATIM (proven 1.31 us/step) + chunk gates.
//   blocks 256..447: xproj GEMM (R6-proven), t-chunk-major, release-fenced
//                    per-chunk tile counters in ctrl[0..3].
__global__ __launch_bounds__(512, 4) void rnn_fused(
    const float* __restrict__ x, const float* __restrict__ Wih,
    const float* __restrict__ Whh, float* __restrict__ out,
    unsigned long long* __restrict__ ex, int* __restrict__ ctrl) {
  const int blk = blockIdx.x;
  const int tid = threadIdx.x;

  if (blk >= 256) {
    // ================= xproj role (R6-proven structure) =================
    __shared__ float xt[32][132];
    __shared__ float wt[32][132];
    const int tm2 = tid >> 5;   // 0..15 -> 8 m-rows each
    const int tn2 = tid & 31;   // 0..31 -> 4 n-cols each
    for (int tau = blk - 256; tau < 1024; tau += 192) {
      const int tc = tau >> 8;          // t-chunk; chunk-0 tiles first
      const int j  = tau & 255;
      const int bb = j >> 2;
      const int bn = j & 3;
      const int bm = bb * 4 + tc;       // row-block: batch bb, t-range tc*128..
      const int m0 = bm << 7;
      const int nn0 = bn << 7;

      float acc[8][4];
#pragma unroll
      for (int i = 0; i < 8; ++i)
#pragma unroll
        for (int jj = 0; jj < 4; ++jj) acc[i][jj] = 0.f;

      for (int ko2 = 0; ko2 < NIN_; ko2 += 32) {
#pragma unroll
        for (int it = 0; it < 2; ++it) {
          const int fidx = it * 512 + tid;
          const int mm = fidx >> 3;
          const int k4 = (fidx & 7) << 2;
          const float4 vx = *(const float4*)(x + (size_t)(m0 + mm) * NIN_ + ko2 + k4);
          xt[k4 + 0][mm] = vx.x; xt[k4 + 1][mm] = vx.y;
          xt[k4 + 2][mm] = vx.z; xt[k4 + 3][mm] = vx.w;
          const float4 vw = *(const float4*)(Wih + (size_t)(nn0 + mm) * NIN_ + ko2 + k4);
          wt[k4 + 0][mm] = vw.x; wt[k4 + 1][mm] = vw.y;
          wt[k4 + 2][mm] = vw.z; wt[k4 + 3][mm] = vw.w;
        }
        __syncthreads();
#pragma unroll 4
        for (int kk = 0; kk < 32; ++kk) {
          float a[8], bb2[4];
          *(float4*)&a[0] = *(const float4*)&xt[kk][8 * tm2];
          *(float4*)&a[4] = *(const float4*)&xt[kk][8 * tm2 + 4];
          *(float4*)&bb2[0] = *(const float4*)&wt[kk][4 * tn2];
#pragma unroll
          for (int i = 0; i < 8; ++i)
#pragma unroll
            for (int jj = 0; jj < 4; ++jj)
              acc[i][jj] = fmaf(a[i], bb2[jj], acc[i][jj]);
        }
        __syncthreads();
      }
#pragma unroll
      for (int i = 0; i < 8; ++i)
        *(float4*)(out + (size_t)(m0 + 8 * tm2 + i) * N_ + nn0 + 4 * tn2) =
            make_float4(acc[i][0], acc[i][1], acc[i][2], acc[i][3]);
      __threadfence();       // payload stores agent-visible
      __syncthreads();       // all threads' fences done
      if (tid == 0)
        __hip_atomic_fetch_add(&ctrl[tc], 1, __ATOMIC_RELEASE,
                               __HIP_MEMORY_SCOPE_AGENT);
    }
    return;
  }

  // ================= scan role (R4 VERBATIM + chunk gates) =================
  const int xcd = blk & 7;
  const int rest = blk >> 3;
  const int m = rest & 3;                 // slice 0..3 (128 neurons)
  const int b = xcd + ((rest >> 2) << 3); // batch 0..63
  const int wv = tid >> 6;
  const int lane = tid & 63;
  const int q = lane & 3;                 // k-quarter
  const int nn = wv * 16 + (lane >> 2);   // neuron-in-slice 0..127
  const int gn = m * 128 + nn;            // global neuron

  __shared__ __align__(16) unsigned int thp[2][256];  // tanh(h) f16x2, dbuf

  float* outb = out + (size_t)b * T_ * N_;
  unsigned long long* exb = ex + (size_t)b * 1024;    // [2 slots][512]

  // weights: pairs k = q*128 .. q*128+127 of row gn -> 64 packed u32
  unsigned int w[64];
  {
    const float* wr = Whh + (size_t)gn * N_ + q * 128;
#pragma unroll
    for (int j = 0; j < 64; ++j) {
      float2 v = *(const float2*)(wr + 2 * j);
      w[j] = packh2(v.x, v.y);
    }
  }

  // gate on xproj chunk 0 (covers h_1 row and xp rows t<128)
  if (tid == 0) {
    while (__hip_atomic_load(&ctrl[0], __ATOMIC_ACQUIRE,
                             __HIP_MEMORY_SCOPE_AGENT) < 256)
      __builtin_amdgcn_s_sleep(1);
  }
  __syncthreads();

  // init thp[0] from h_1 = out[b][0][:]
  if (tid < 256) {
    float2 h0 = *(const float2*)(outb + 2 * tid);
    thp[0][thp_idx(tid)] = packh2(fast_tanh(h0.x), fast_tanh(h0.y));
  }

  // poller assignment: tid<384 polls one remote neuron's published y
  const int pv = tid & 127;
  const int sr = tid >> 7;                 // 0..2 for pollers
  const int sm = sr + (sr >= m ? 1 : 0);   // actual remote slice
  const int prn = sm * 128 + pv;           // remote global neuron

  __syncthreads();

  for (int t = 1; t < T_; ++t) {
    if ((t & 127) == 0) {                  // xp chunk gate (t = 128, 256, 384)
      if (tid == 0) {
        while (__hip_atomic_load(&ctrl[t >> 7], __ATOMIC_ACQUIRE,
                                 __HIP_MEMORY_SCOPE_AGENT) < 256)
          __builtin_amdgcn_s_sleep(1);
      }
      __syncthreads();
    }

    // xp prefetch (q0 lanes; consumed after the reduce)
    float xp = 0.f;
    if (q == 0) xp = outb[(size_t)t * N_ + gn];

    // poll remote y_{t-1}, tanh it, pack into thp[(t-1)&1]
    if (t >= 2 && tid < 384) {
      unsigned long long v;
      do {
        v = __hip_atomic_load(&exb[((t - 1) & 1) * 512 + prn],
                              __ATOMIC_RELAXED, __HIP_MEMORY_SCOPE_AGENT);
      } while ((unsigned int)(v >> 32) != (unsigned int)(t - 1));
      const float th = fast_tanh(__uint_as_float((unsigned int)v));
      const float thn = __shfl_xor(th, 1);
      if ((tid & 1) == 0) thp[(t - 1) & 1][thp_idx(prn >> 1)] = packh2(th, thn);
    }
    __syncthreads();   // A: thp[(t-1)&1] complete

    const uint4* tq = (const uint4*)&thp[(t - 1) & 1][0];
    float acc = 0.f;
#pragma unroll
    for (int j4 = 0; j4 < 16; ++j4) {
      const uint4 tv = tq[j4 * 4 + q];   // 4 distinct addrs, disjoint banks
      acc = dot2acc(w[4 * j4 + 0], tv.x, acc);
      acc = dot2acc(w[4 * j4 + 1], tv.y, acc);
      acc = dot2acc(w[4 * j4 + 2], tv.z, acc);
      acc = dot2acc(w[4 * j4 + 3], tv.w, acc);
    }
    acc += __shfl_xor(acc, 1);
    acc += __shfl_xor(acc, 2);   // all 4 quarter-lanes hold the full dot

    float th_own = 0.f;
    if (q == 0) {
      const float y = acc + xp;
      // publish FIRST: this is the cross-CU critical path
      __hip_atomic_store(&exb[(t & 1) * 512 + gn],
                         ((unsigned long long)(unsigned int)t << 32) |
                             (unsigned long long)__float_as_uint(y),
                         __ATOMIC_RELAXED, __HIP_MEMORY_SCOPE_AGENT);
      __builtin_nontemporal_store(y, &outb[(size_t)t * N_ + gn]);
      th_own = fast_tanh(y);
    }
    const float th_nb = __shfl_xor(th_own, 4);   // neighbor neuron's tanh
    if ((lane & 7) == 0)                          // q==0 and even neuron
      thp[t & 1][thp_idx(gn >> 1)] = packh2(th_own, th_nb);
    // next iteration's barrier A provides separation (double buffer)
  }
}

extern "C" void kernel_launch(void* const* d_in, const int* in_sizes, int n_in,
                              void* d_out, int out_size, void* d_ws, size_t ws_size,
                              hipStream_t stream) {
  const float* x   = (const float*)d_in[0];
  const float* Wih = (const float*)d_in[1];
  const float* Whh = (const float*)d_in[2];
  float* out = (float*)d_out;
  unsigned long long* ex = (unsigned long long*)d_ws;   // 512 KiB exchange
  int* ctrl = (int*)((char*)d_ws + 524288);             // 4 chunk flags

  hipMemsetAsync(d_ws, 0, 524288 + 64, stream);
  rnn_fused<<<448, 512, 0, stream>>>(x, Wih, Whh, out, ex, ctrl);
}

// Round 14
// 1096.407 us; speedup vs baseline: 2.3266x; 1.0519x over previous
//
#include <hip/hip_runtime.h>
#include <stdint.h>

#define B_   64
#define T_   512
#define NIN_ 256
#define N_   512

typedef _Float16 half2_t __attribute__((ext_vector_type(2)));

#if defined(__has_builtin)
#if __has_builtin(__builtin_amdgcn_fdot2)
#define HAVE_FDOT2 1
#endif
#endif

__device__ __forceinline__ float dot2acc(unsigned int a, unsigned int b, float c) {
#ifdef HAVE_FDOT2
  return __builtin_amdgcn_fdot2(__builtin_bit_cast(half2_t, a),
                                __builtin_bit_cast(half2_t, b), c, false);
#else
  half2_t ha = __builtin_bit_cast(half2_t, a), hb = __builtin_bit_cast(half2_t, b);
  c += (float)ha[0] * (float)hb[0];
  c += (float)ha[1] * (float)hb[1];
  return c;
#endif
}

__device__ __forceinline__ float fast_tanh(float x) {
  float e = __expf(2.0f * x);
  return 1.0f - 2.0f / (e + 1.0f);
}
__device__ __forceinline__ unsigned int packh2(float a, float b) {
  half2_t h; h[0] = (_Float16)a; h[1] = (_Float16)b;
  return __builtin_bit_cast(unsigned int, h);
}

// Quarter-interleaved LDS index for tanh pair p (conflict-free b128 broadcast)
__device__ __forceinline__ int thp_idx(int p) {
  return (((p >> 2) & 15) << 4) + ((p >> 6) << 2) + (p & 3);
}

// Fused kernel, 448 blocks x 512 thr.
// amdgpu_waves_per_eu(4,4) pins the allocator to EXACTLY 4 waves/EU:
//   - budget = 512/4 = 128 VGPR  -> the scan's w[64] array stays resident
//     (R13: min-only bound let the allocator pick 64 VGPR -> w[] spilled)
//   - 16 waves/CU = 2 blocks/CU  -> all 448 blocks co-resident (448<=512)
//     (R12: 1 block/CU -> xproj never launched -> deadlock)
//   blocks 0..255  : R4 scan VERBATIM (proven 1.31 us/step) + chunk gates.
//   blocks 256..447: xproj GEMM (R6-proven), t-chunk-major, release-fenced
//                    per-chunk tile counters in ctrl[0..3].
__global__ void __launch_bounds__(512)
__attribute__((amdgpu_waves_per_eu(4, 4))) rnn_fused(
    const float* __restrict__ x, const float* __restrict__ Wih,
    const float* __restrict__ Whh, float* __restrict__ out,
    unsigned long long* __restrict__ ex, int* __restrict__ ctrl) {
  const int blk = blockIdx.x;
  const int tid = threadIdx.x;

  if (blk >= 256) {
    // ================= xproj role (R6-proven structure) =================
    __shared__ float xt[32][132];
    __shared__ float wt[32][132];
    const int tm2 = tid >> 5;   // 0..15 -> 8 m-rows each
    const int tn2 = tid & 31;   // 0..31 -> 4 n-cols each
    for (int tau = blk - 256; tau < 1024; tau += 192) {
      const int tc = tau >> 8;          // t-chunk; chunk-0 tiles first
      const int j  = tau & 255;
      const int bb = j >> 2;
      const int bn = j & 3;
      const int bm = bb * 4 + tc;       // row-block: batch bb, t-range tc*128..
      const int m0 = bm << 7;
      const int nn0 = bn << 7;

      float acc[8][4];
#pragma unroll
      for (int i = 0; i < 8; ++i)
#pragma unroll
        for (int jj = 0; jj < 4; ++jj) acc[i][jj] = 0.f;

      for (int ko2 = 0; ko2 < NIN_; ko2 += 32) {
#pragma unroll
        for (int it = 0; it < 2; ++it) {
          const int fidx = it * 512 + tid;
          const int mm = fidx >> 3;
          const int k4 = (fidx & 7) << 2;
          const float4 vx = *(const float4*)(x + (size_t)(m0 + mm) * NIN_ + ko2 + k4);
          xt[k4 + 0][mm] = vx.x; xt[k4 + 1][mm] = vx.y;
          xt[k4 + 2][mm] = vx.z; xt[k4 + 3][mm] = vx.w;
          const float4 vw = *(const float4*)(Wih + (size_t)(nn0 + mm) * NIN_ + ko2 + k4);
          wt[k4 + 0][mm] = vw.x; wt[k4 + 1][mm] = vw.y;
          wt[k4 + 2][mm] = vw.z; wt[k4 + 3][mm] = vw.w;
        }
        __syncthreads();
#pragma unroll 4
        for (int kk = 0; kk < 32; ++kk) {
          float a[8], bb2[4];
          *(float4*)&a[0] = *(const float4*)&xt[kk][8 * tm2];
          *(float4*)&a[4] = *(const float4*)&xt[kk][8 * tm2 + 4];
          *(float4*)&bb2[0] = *(const float4*)&wt[kk][4 * tn2];
#pragma unroll
          for (int i = 0; i < 8; ++i)
#pragma unroll
            for (int jj = 0; jj < 4; ++jj)
              acc[i][jj] = fmaf(a[i], bb2[jj], acc[i][jj]);
        }
        __syncthreads();
      }
#pragma unroll
      for (int i = 0; i < 8; ++i)
        *(float4*)(out + (size_t)(m0 + 8 * tm2 + i) * N_ + nn0 + 4 * tn2) =
            make_float4(acc[i][0], acc[i][1], acc[i][2], acc[i][3]);
      __threadfence();       // payload stores agent-visible
      __syncthreads();       // all threads' fences done
      if (tid == 0)
        __hip_atomic_fetch_add(&ctrl[tc], 1, __ATOMIC_RELEASE,
                               __HIP_MEMORY_SCOPE_AGENT);
    }
    return;
  }

  // ================= scan role (R4 VERBATIM + chunk gates) =================
  const int xcd = blk & 7;
  const int rest = blk >> 3;
  const int m = rest & 3;                 // slice 0..3 (128 neurons)
  const int b = xcd + ((rest >> 2) << 3); // batch 0..63
  const int wv = tid >> 6;
  const int lane = tid & 63;
  const int q = lane & 3;                 // k-quarter
  const int nn = wv * 16 + (lane >> 2);   // neuron-in-slice 0..127
  const int gn = m * 128 + nn;            // global neuron

  __shared__ __align__(16) unsigned int thp[2][256];  // tanh(h) f16x2, dbuf

  float* outb = out + (size_t)b * T_ * N_;
  unsigned long long* exb = ex + (size_t)b * 1024;    // [2 slots][512]

  // weights: pairs k = q*128 .. q*128+127 of row gn -> 64 packed u32
  unsigned int w[64];
  {
    const float* wr = Whh + (size_t)gn * N_ + q * 128;
#pragma unroll
    for (int j = 0; j < 64; ++j) {
      float2 v = *(const float2*)(wr + 2 * j);
      w[j] = packh2(v.x, v.y);
    }
  }

  // gate on xproj chunk 0 (covers h_1 row and xp rows t<128)
  if (tid == 0) {
    while (__hip_atomic_load(&ctrl[0], __ATOMIC_ACQUIRE,
                             __HIP_MEMORY_SCOPE_AGENT) < 256)
      __builtin_amdgcn_s_sleep(1);
  }
  __syncthreads();

  // init thp[0] from h_1 = out[b][0][:]
  if (tid < 256) {
    float2 h0 = *(const float2*)(outb + 2 * tid);
    thp[0][thp_idx(tid)] = packh2(fast_tanh(h0.x), fast_tanh(h0.y));
  }

  // poller assignment: tid<384 polls one remote neuron's published y
  const int pv = tid & 127;
  const int sr = tid >> 7;                 // 0..2 for pollers
  const int sm = sr + (sr >= m ? 1 : 0);   // actual remote slice
  const int prn = sm * 128 + pv;           // remote global neuron

  __syncthreads();

  for (int t = 1; t < T_; ++t) {
    if ((t & 127) == 0) {                  // xp chunk gate (t = 128, 256, 384)
      if (tid == 0) {
        while (__hip_atomic_load(&ctrl[t >> 7], __ATOMIC_ACQUIRE,
                                 __HIP_MEMORY_SCOPE_AGENT) < 256)
          __builtin_amdgcn_s_sleep(1);
      }
      __syncthreads();
    }

    // xp prefetch (q0 lanes; consumed after the reduce)
    float xp = 0.f;
    if (q == 0) xp = outb[(size_t)t * N_ + gn];

    // poll remote y_{t-1}, tanh it, pack into thp[(t-1)&1]
    if (t >= 2 && tid < 384) {
      unsigned long long v;
      do {
        v = __hip_atomic_load(&exb[((t - 1) & 1) * 512 + prn],
                              __ATOMIC_RELAXED, __HIP_MEMORY_SCOPE_AGENT);
      } while ((unsigned int)(v >> 32) != (unsigned int)(t - 1));
      const float th = fast_tanh(__uint_as_float((unsigned int)v));
      const float thn = __shfl_xor(th, 1);
      if ((tid & 1) == 0) thp[(t - 1) & 1][thp_idx(prn >> 1)] = packh2(th, thn);
    }
    __syncthreads();   // A: thp[(t-1)&1] complete

    const uint4* tq = (const uint4*)&thp[(t - 1) & 1][0];
    float acc = 0.f;
#pragma unroll
    for (int j4 = 0; j4 < 16; ++j4) {
      const uint4 tv = tq[j4 * 4 + q];   // 4 distinct addrs, disjoint banks
      acc = dot2acc(w[4 * j4 + 0], tv.x, acc);
      acc = dot2acc(w[4 * j4 + 1], tv.y, acc);
      acc = dot2acc(w[4 * j4 + 2], tv.z, acc);
      acc = dot2acc(w[4 * j4 + 3], tv.w, acc);
    }
    acc += __shfl_xor(acc, 1);
    acc += __shfl_xor(acc, 2);   // all 4 quarter-lanes hold the full dot

    float th_own = 0.f;
    if (q == 0) {
      const float y = acc + xp;
      // publish FIRST: this is the cross-CU critical path
      __hip_atomic_store(&exb[(t & 1) * 512 + gn],
                         ((unsigned long long)(unsigned int)t << 32) |
                             (unsigned long long)__float_as_uint(y),
                         __ATOMIC_RELAXED, __HIP_MEMORY_SCOPE_AGENT);
      __builtin_nontemporal_store(y, &outb[(size_t)t * N_ + gn]);
      th_own = fast_tanh(y);
    }
    const float th_nb = __shfl_xor(th_own, 4);   // neighbor neuron's tanh
    if ((lane & 7) == 0)                          // q==0 and even neuron
      thp[t & 1][thp_idx(gn >> 1)] = packh2(th_own, th_nb);
    // next iteration's barrier A provides separation (double buffer)
  }
}

extern "C" void kernel_launch(void* const* d_in, const int* in_sizes, int n_in,
                              void* d_out, int out_size, void* d_ws, size_t ws_size,
                              hipStream_t stream) {
  const float* x   = (const float*)d_in[0];
  const float* Wih = (const float*)d_in[1];
  const float* Whh = (const float*)d_in[2];
  float* out = (float*)d_out;
  unsigned long long* ex = (unsigned long long*)d_ws;   // 512 KiB exchange
  int* ctrl = (int*)((char*)d_ws + 524288);             // 4 chunk flags

  hipMemsetAsync(d_ws, 0, 524288 + 64, stream);
  rnn_fused<<<448, 512, 0, stream>>>(x, Wih, Whh, out, ex, ctrl);
}